// Round 11
// baseline (335.242 us; speedup 1.0000x reference)
//
#include <hip/hip_runtime.h>
#include <stdint.h>

namespace {

constexpr int B = 8;
constexpr int H = 1024;
constexpr int W = 1024;
constexpr int TOPK = 4096;
constexpr int CAND_CAP = 131072;  // per batch
constexpr int SEL_CAP = 8192;     // per batch (expected n ~ 6k)
constexpr int LIST_CAP = 320;     // per 64x64 tile (avg ~164 survivors; fallback below)
constexpr int HIST_N = 32768;     // 17-bit key prefix = score_bits>>15

// fused-NMS tile (R7-bench winner): 64x64 interior, radius-12 staged halo, rows
// padded to 92. Masks bitpacked 1 bit/px in u32 words, suppression applied
// on-the-fly inside score passes; S stays original (emit reads it directly).
constexpr int RROWS = 92;   // staged score rows
constexpr int NG = 22;      // float4 col-groups (88 cols)
constexpr int STR = 88;     // score row stride (floats)
constexpr int MW4 = 4;      // bitpacked mask words per row (96 bits; word 3 = pad)
constexpr int NSTRIP = 11;  // 11 strips x 8 output rows = rows 2..89
constexpr int NUNIT = NG * NSTRIP;  // 242 <= 256

// rank kernel tiling (R9-bench winner: me x chunk tiled grid, 2048 blocks)
constexpr int RK_ME = 256;
constexpr int RK_CH = 1024;

// workspace layout (bytes)
constexpr size_t OFF_CNT   = 0;                                    // 4 KiB
constexpr size_t OFF_GHIST = 4096;                                 // B*HIST_N*4 = 1 MiB
constexpr size_t OFF_RANK  = OFF_GHIST + (size_t)B * HIST_N * 4;   // B*SEL_CAP*4 = 256 KiB
constexpr size_t OFF_SEL   = OFF_RANK + (size_t)B * SEL_CAP * 4;   // B*SEL_CAP*8 = 512 KiB
constexpr size_t OFF_CAND  = OFF_SEL + (size_t)B * SEL_CAP * 8;    // 8 MiB
constexpr size_t ZERO_BYTES = OFF_SEL;  // cnt page + ghist + rank

__device__ __forceinline__ float max5(float a, float b, float c, float d, float e) {
  return fmaxf(fmaxf(fmaxf(a, b), fmaxf(c, d)), e);
}
__device__ __forceinline__ float4 ld4(const float* p) {
  return *reinterpret_cast<const float4*>(p);
}

// One unit: col-group G in [0,22), strip s in [0,11) -> staged rows r0..r0+7.
// PASS 0: mask0 = (sc == max5x5(sc)) & valid          -> atomicOr MA
// PASS 1: mask1 = mask0 | (newmax(sup?0:sc) & ~sup1)  -> atomicOr MA (in place)
// PASS 2: final = mask1 | (newmax(sup?0:sc) & ~sup2)  -> emit keys
template <int PASS>
__device__ __forceinline__ void score_pass(
    int u, int x0, int y0, const float* __restrict__ S,
    const uint32_t* __restrict__ SUP, uint32_t* __restrict__ MA,
    uint64_t* list, uint32_t* cnt_loc, uint64_t* cand, uint32_t* cand_count,
    uint32_t* gh, int b) {
  const int G = u % NG, s = u / NG;
  const int r0 = 2 + 8 * s;
  const int gx0 = x0 - 12 + 4 * G;
  uint32_t colm = 0;
#pragma unroll
  for (int j = 0; j < 4; ++j)
    if ((unsigned)(gx0 + j) < (unsigned)W) colm |= 1u << j;
  // suppression window: bits 0..3 -> cols of a, 4..7 -> d, 8..11 -> e
  const int p = 4 * G - 4;
  const int pw = (p < 0) ? 0 : (p >> 5);
  const int psh = (p < 0) ? 0 : (p & 31);
  const int pls = (p < 0) ? -p : 0;

  float4 hw[5], cw[5];
  uint32_t sn[5];
#pragma unroll
  for (int k = 0; k < 12; ++k) {
    const int rr = r0 - 2 + k;
    const float* rowp = S + rr * STR + 4 * G;
    float4 d = ld4(rowp);
    float4 a = (G > 0) ? ld4(rowp - 4) : d;  // garbage-only cols, safe
    float4 e = (G < NG - 1) ? ld4(rowp + 4) : d;
    uint32_t supn = 0;
    if (PASS != 0) {
      const uint32_t* srow = SUP + rr * MW4;
      uint64_t X = (uint64_t)srow[pw] | ((uint64_t)srow[pw + 1] << 32);
      uint64_t win = pls ? (X << pls) : (X >> psh);
      if (win & 0x001u) a.x = 0.f;
      if (win & 0x002u) a.y = 0.f;
      if (win & 0x004u) a.z = 0.f;
      if (win & 0x008u) a.w = 0.f;
      if (win & 0x010u) d.x = 0.f;
      if (win & 0x020u) d.y = 0.f;
      if (win & 0x040u) d.z = 0.f;
      if (win & 0x080u) d.w = 0.f;
      if (win & 0x100u) e.x = 0.f;
      if (win & 0x200u) e.y = 0.f;
      if (win & 0x400u) e.z = 0.f;
      if (win & 0x800u) e.w = 0.f;
      supn = (uint32_t)(win >> 4) & 0xFu;
    }
    float4 hm;
    hm.x = max5(a.z, a.w, d.x, d.y, d.z);
    hm.y = max5(a.w, d.x, d.y, d.z, d.w);
    hm.z = max5(d.x, d.y, d.z, d.w, e.x);
    hm.w = max5(d.y, d.z, d.w, e.x, e.y);
    hw[k % 5] = hm;
    cw[k % 5] = d;
    sn[k % 5] = supn;
    if (k >= 4) {
      const int rq = r0 + k - 4;
      const int gy = y0 - 12 + rq;
      float4 vm;
      vm.x = max5(hw[0].x, hw[1].x, hw[2].x, hw[3].x, hw[4].x);
      vm.y = max5(hw[0].y, hw[1].y, hw[2].y, hw[3].y, hw[4].y);
      vm.z = max5(hw[0].z, hw[1].z, hw[2].z, hw[3].z, hw[4].z);
      vm.w = max5(hw[0].w, hw[1].w, hw[2].w, hw[3].w, hw[4].w);
      float4 c = cw[(k + 3) % 5];  // center row rq (masked value for PASS 1/2)
      uint32_t nm = (uint32_t)(c.x == vm.x) | ((uint32_t)(c.y == vm.y) << 1) |
                    ((uint32_t)(c.z == vm.z) << 2) | ((uint32_t)(c.w == vm.w) << 3);
      nm &= ((unsigned)gy < (unsigned)H) ? colm : 0u;
      const int widx = rq * MW4 + (G >> 3);
      const int shift = 4 * (G & 7);
      if (PASS == 0) {
        if (nm) atomicOr(&MA[widx], nm << shift);
      } else if (PASS == 1) {
        uint32_t v = nm & ~sn[(k + 3) % 5];
        if (v) atomicOr(&MA[widx], v << shift);
      } else {
        uint32_t fin = ((MA[widx] >> shift) & 0xFu) | (nm & ~sn[(k + 3) % 5]);
        if (fin && G >= 3 && G < 19 && rq >= 12 && rq < 76 && gy >= 2 && gy < H - 2) {
#pragma unroll
          for (int j = 0; j < 4; ++j) {
            if ((fin >> j) & 1u) {
              int gx = gx0 + j;
              if (gx >= 2 && gx < W - 2) {
                float sval = S[rq * STR + 4 * G + j];  // original (unmasked) score
                if (sval > 0.0f) {
                  uint32_t bits = __float_as_uint(sval);
                  uint32_t flat = (uint32_t)(gy * W + gx);
                  uint64_t key = ((uint64_t)bits << 32) | (uint64_t)(0xFFFFFFFFu - flat);
                  uint32_t pos = atomicAdd(cnt_loc, 1u);
                  if (pos < (uint32_t)LIST_CAP) {
                    list[pos] = key;
                  } else {  // tie overflow: direct global append (rare)
                    uint32_t pp = atomicAdd(&cand_count[b], 1u);
                    if (pp < (uint32_t)CAND_CAP) {
                      cand[(size_t)b * CAND_CAP + pp] = key;
                      atomicAdd(&gh[bits >> 15], 1u);  // fused histogram
                    }
                  }
                }
              }
            }
          }
        }
      }
    }
  }
}

// bit-dilate r=2: SOUT |= any(MIN in 5x5) & valid (nibble per (row, G))
__device__ __forceinline__ void dilate_pass(int u, int x0, int y0,
                                            const uint32_t* __restrict__ MIN_,
                                            uint32_t* __restrict__ SOUT) {
  const int G = u % NG, s = u / NG;
  const int r0 = 2 + 8 * s;
  const int gx0 = x0 - 12 + 4 * G;
  uint32_t colm = 0;
#pragma unroll
  for (int j = 0; j < 4; ++j)
    if ((unsigned)(gx0 + j) < (unsigned)W) colm |= 1u << j;
  const int p = 4 * G - 2;  // window bit m = staged col p+m
  const int pw = (p < 0) ? 0 : (p >> 5);
  const int psh = (p < 0) ? 0 : (p & 31);
  const int pls = (p < 0) ? -p : 0;
  uint32_t ring[5];
#pragma unroll
  for (int k = 0; k < 12; ++k) {
    const int rr = r0 - 2 + k;
    const uint32_t* srow = MIN_ + rr * MW4;
    uint64_t X = (uint64_t)srow[pw] | ((uint64_t)srow[pw + 1] << 32);
    uint64_t win = pls ? (X << pls) : (X >> psh);
    uint64_t t = win | (win >> 1) | (win >> 2) | (win >> 3) | (win >> 4);
    ring[k % 5] = (uint32_t)t & 0xFu;
    if (k >= 4) {
      const int rq = r0 + k - 4;
      const int gy = y0 - 12 + rq;
      uint32_t nib = ring[0] | ring[1] | ring[2] | ring[3] | ring[4];
      nib &= ((unsigned)gy < (unsigned)H) ? colm : 0u;
      if (nib) atomicOr(&SOUT[rq * MW4 + (G >> 3)], nib << (4 * (G & 7)));
    }
  }
}

// ---------------- fused 5-pass NMS + candidate emit + histogram ----------------------
__global__ void __launch_bounds__(256, 4) k_nms(const float* __restrict__ scores,
                                                uint64_t* __restrict__ cand,
                                                uint32_t* __restrict__ cand_count,
                                                uint32_t* __restrict__ ghist) {
  __shared__ float S[RROWS * STR];        // 32.4 KB
  __shared__ uint32_t MAs[RROWS * MW4];   // 1.47 KB (mask0, then mask1 in place)
  __shared__ uint32_t SP1[RROWS * MW4];   // 1.47 KB
  __shared__ uint32_t SP2[RROWS * MW4];   // 1.47 KB
  __shared__ uint64_t list[LIST_CAP];     // 2.5 KB   -> total 39.4 KB, 4 blk/CU
  __shared__ uint32_t cnt_loc, base_g;
  const int b = blockIdx.z;
  const int x0 = blockIdx.x * 64, y0 = blockIdx.y * 64;
  const int tid = threadIdx.x;
  const float* img = scores + (size_t)b * H * W;
  uint32_t* gh = ghist + (size_t)b * HIST_N;
  if (tid == 0) cnt_loc = 0;

  for (int u = tid; u < RROWS * NG; u += 256) {
    int r = u / NG, G = u % NG;
    int gy = y0 - 12 + r, gx = x0 - 12 + 4 * G;
    float4 v;
    if ((unsigned)gy < (unsigned)H && (unsigned)gx < (unsigned)W)
      v = ld4(img + (size_t)gy * W + gx);
    else
      v = make_float4(-INFINITY, -INFINITY, -INFINITY, -INFINITY);
    *reinterpret_cast<float4*>(&S[r * STR + 4 * G]) = v;
  }
  for (int i = tid; i < RROWS * MW4; i += 256) {
    MAs[i] = 0;
    SP1[i] = 0;
    SP2[i] = 0;
  }
  __syncthreads();
  if (tid < NUNIT)
    score_pass<0>(tid, x0, y0, S, nullptr, MAs, nullptr, nullptr, nullptr, nullptr,
                  nullptr, b);
  __syncthreads();
  if (tid < NUNIT) dilate_pass(tid, x0, y0, MAs, SP1);
  __syncthreads();
  if (tid < NUNIT)
    score_pass<1>(tid, x0, y0, S, SP1, MAs, nullptr, nullptr, nullptr, nullptr,
                  nullptr, b);
  __syncthreads();
  if (tid < NUNIT) dilate_pass(tid, x0, y0, MAs, SP2);
  __syncthreads();
  if (tid < NUNIT)
    score_pass<2>(tid, x0, y0, S, SP2, MAs, list, &cnt_loc, cand, cand_count, gh, b);
  __syncthreads();
  uint32_t nblk = cnt_loc;
  uint32_t nmain = nblk < (uint32_t)LIST_CAP ? nblk : (uint32_t)LIST_CAP;
  if (tid == 0) base_g = atomicAdd(&cand_count[b], nmain);
  __syncthreads();
  uint32_t bg = base_g;
  for (uint32_t i = tid; i < nmain; i += 256) {
    uint32_t pp = bg + i;
    if (pp < (uint32_t)CAND_CAP) {
      uint64_t kk = list[i];
      cand[(size_t)b * CAND_CAP + pp] = kk;
      atomicAdd(&gh[(uint32_t)(kk >> 47)], 1u);  // fused histogram (fire-and-forget)
    }
  }
}

// ---------------- zero scratch -------------------------------------------------------
__global__ void __launch_bounds__(256) k_zero(float4* __restrict__ p, int n4) {
  int i = blockIdx.x * 256 + threadIdx.x;
  const int stride = gridDim.x * 256;
  const float4 z = make_float4(0.f, 0.f, 0.f, 0.f);
  for (; i < n4; i += stride) p[i] = z;
}

// ---------------- find threshold bucket ----------------------------------------------
__global__ void __launch_bounds__(1024) k_findthr(const uint32_t* __restrict__ ghist,
                                                  uint64_t* __restrict__ thr_key) {
  __shared__ uint32_t part[1024];
  __shared__ int shT;
  __shared__ uint32_t sh_above;
  const int b = blockIdx.x, t = threadIdx.x;
  const uint32_t* gh = ghist + (size_t)b * HIST_N;
  uint32_t s = 0;
#pragma unroll 4
  for (int i = 0; i < 32; ++i) s += gh[t * 32 + i];
  part[t] = s;
  if (t == 0) { shT = -1; sh_above = 0; }
  __syncthreads();
  for (int d = 1; d < 1024; d <<= 1) {  // suffix sum: part[t] = sum_{t'>=t}
    uint32_t v = (t + d < 1024) ? part[t + d] : 0u;
    __syncthreads();
    part[t] += v;
    __syncthreads();
  }
  if (part[0] < (uint32_t)TOPK) {
    if (t == 0) thr_key[b] = 0ull;  // fewer than TOPK candidates: select all
    return;
  }
  {
    uint32_t mine = part[t];
    uint32_t nxt = (t + 1 < 1024) ? part[t + 1] : 0u;
    if (mine >= (uint32_t)TOPK && nxt < (uint32_t)TOPK) { shT = t; sh_above = nxt; }
  }
  __syncthreads();
  if (t == 0) {
    const int T = shT;
    uint32_t run = sh_above;
    int bkt = T * 32;
    for (int i = 31; i >= 0; --i) {
      run += gh[T * 32 + i];
      if (run >= (uint32_t)TOPK) { bkt = T * 32 + i; break; }
    }
    thr_key[b] = (uint64_t)bkt << 47;
  }
}

// ---------------- compact ------------------------------------------------------------
__global__ void __launch_bounds__(1024) k_compact(const uint64_t* __restrict__ cand,
                                                  const uint32_t* __restrict__ cand_count,
                                                  const uint64_t* __restrict__ thr_key,
                                                  uint64_t* __restrict__ sel,
                                                  uint32_t* __restrict__ sel_count) {
  __shared__ uint64_t list[1024];
  __shared__ uint32_t cnt_loc;
  __shared__ uint32_t base_g;
  const int b = blockIdx.y;
  uint32_t n = cand_count[b];
  if (n > (uint32_t)CAND_CAP) n = CAND_CAP;
  const int tid = threadIdx.x;
  if (tid == 0) cnt_loc = 0;
  __syncthreads();
  uint32_t i = blockIdx.x * 1024 + tid;
  if (i < n) {
    uint64_t key = cand[(size_t)b * CAND_CAP + i];
    if (key >= thr_key[b]) {
      uint32_t pos = atomicAdd(&cnt_loc, 1u);
      list[pos] = key;
    }
  }
  __syncthreads();
  uint32_t nblk = cnt_loc;
  if (tid == 0 && nblk > 0) base_g = atomicAdd(&sel_count[b], nblk);
  __syncthreads();
  if (nblk > 0 && (uint32_t)tid < nblk) {
    uint32_t pp = base_g + tid;
    if (pp < (uint32_t)SEL_CAP) sel[(size_t)b * SEL_CAP + pp] = list[tid];
  }
}

// ---------------- tiled partial ranking (R9-bench winner) ----------------------------
// rank[me] = #{keys > me}; keys distinct => permutation => exact JAX top_k order.
__global__ void __launch_bounds__(RK_ME) k_rank_part(const uint64_t* __restrict__ sel,
                                                     const uint32_t* __restrict__ sel_count,
                                                     uint32_t* __restrict__ rankg) {
  __shared__ uint64_t keys[RK_CH];  // 8 KiB
  const int b = blockIdx.z;
  uint32_t n = sel_count[b];
  if (n > (uint32_t)SEL_CAP) n = SEL_CAP;
  const uint32_t me0 = blockIdx.x * RK_ME;
  const uint32_t c0 = blockIdx.y * RK_CH;
  if (me0 >= n || c0 >= n) return;
  const uint64_t* sb = sel + (size_t)b * SEL_CAP;
  uint32_t clen = n - c0;
  if (clen > (uint32_t)RK_CH) clen = RK_CH;
  for (uint32_t i = threadIdx.x; i < clen; i += RK_ME) keys[i] = sb[c0 + i];
  __syncthreads();
  const uint32_t me = me0 + threadIdx.x;
  if (me >= n) return;
  const uint64_t kme = sb[me];
  uint32_t rank = 0;
  uint32_t i = 0;
  for (; i + 8 <= clen; i += 8) {
    rank += (keys[i] > kme);
    rank += (keys[i + 1] > kme);
    rank += (keys[i + 2] > kme);
    rank += (keys[i + 3] > kme);
    rank += (keys[i + 4] > kme);
    rank += (keys[i + 5] > kme);
    rank += (keys[i + 6] > kme);
    rank += (keys[i + 7] > kme);
  }
  for (; i < clen; ++i) rank += (keys[i] > kme);
  if (rank) atomicAdd(&rankg[(size_t)b * SEL_CAP + me], rank);
}

// ---------------- refinement fused with scatter: 8 lanes per selected key ------------
__global__ void __launch_bounds__(256) k_refine(const float* __restrict__ scores,
                                                const uint64_t* __restrict__ sel,
                                                const uint32_t* __restrict__ sel_count,
                                                const uint32_t* __restrict__ rankg,
                                                float* __restrict__ out) {
  const int b = blockIdx.y;
  uint32_t n = sel_count[b];
  if (n > (uint32_t)SEL_CAP) n = SEL_CAP;
  int gid = blockIdx.x * 256 + threadIdx.x;
  int si = gid >> 3, ln = gid & 7;
  if ((uint32_t)si >= n) return;
  uint32_t r = rankg[(size_t)b * SEL_CAP + si];
  if (r >= (uint32_t)TOPK) return;
  uint64_t key = sel[(size_t)b * SEL_CAP + si];
  uint32_t flat = 0xFFFFFFFFu - (uint32_t)(key & 0xFFFFFFFFull);
  if (flat >= (uint32_t)(H * W)) flat = 0;
  const int ix = (int)(flat % W);
  const int iy = (int)(flat / W);
  const float* img = scores + (size_t)b * H * W;

  const int nt = (ln == 0) ? 4 : 3;
  float v[4];
  float mymax = -INFINITY;
#pragma unroll
  for (int i = 0; i < 4; ++i) {
    if (i < nt) {
      int t = ln + 8 * i;
      int y = iy + t / 5 - 2, x = ix + t % 5 - 2;
      float val = ((unsigned)x < (unsigned)W && (unsigned)y < (unsigned)H)
                      ? img[(size_t)y * W + x] : 0.0f;
      v[i] = val;
      mymax = fmaxf(mymax, val);
    }
  }
#pragma unroll
  for (int m = 1; m < 8; m <<= 1) mymax = fmaxf(mymax, __shfl_xor(mymax, m));
  float e[4];
  float sum = 0.f, sx = 0.f, sy = 0.f;
#pragma unroll
  for (int i = 0; i < 4; ++i) {
    if (i < nt) {
      int t = ln + 8 * i;
      float ev = expf((v[i] - mymax) / 0.1f);
      e[i] = ev;
      sum += ev;
      sx += ev * (float)(t % 5 - 2);
      sy += ev * (float)(t / 5 - 2);
    }
  }
#pragma unroll
  for (int m = 1; m < 8; m <<= 1) {
    sum += __shfl_xor(sum, m);
    sx += __shfl_xor(sx, m);
    sy += __shfl_xor(sy, m);
  }
  float rx = sx / sum, ry = sy / sum;
  float dsp = 0.f;
#pragma unroll
  for (int i = 0; i < 4; ++i) {
    if (i < nt) {
      int t = ln + 8 * i;
      float dx = ((float)(t % 5 - 2) - rx) * 0.5f;
      float dy = ((float)(t / 5 - 2) - ry) * 0.5f;
      dsp += e[i] * (dx * dx + dy * dy);
    }
  }
#pragma unroll
  for (int m = 1; m < 8; m <<= 1) dsp += __shfl_xor(dsp, m);
  if (ln != 0) return;
  dsp /= sum;
  float kx = ((float)ix + rx) / 1023.0f * 2.0f - 1.0f;
  float ky = ((float)iy + ry) / 1023.0f * 2.0f - 1.0f;
  float px = (kx + 1.0f) * 0.5f * 1023.0f;
  float py = (ky + 1.0f) * 0.5f * 1023.0f;
  float x0f = floorf(px), y0f = floorf(py);
  float wx1 = px - x0f, wx0 = 1.0f - wx1;
  float wy1 = py - y0f, wy0 = 1.0f - wy1;
  int x0 = (int)x0f, y0 = (int)y0f;
  float sc = 0.0f;
  {
    int xs[2] = {x0, x0 + 1};
    int ys[2] = {y0, y0 + 1};
    float wxs[2] = {wx0, wx1};
    float wys[2] = {wy0, wy1};
#pragma unroll
    for (int yy = 0; yy < 2; ++yy)
#pragma unroll
      for (int xx = 0; xx < 2; ++xx) {
        int xi = xs[xx], yi = ys[yy];
        bool valid = (xi >= 0 && xi < W && yi >= 0 && yi < H);
        int xc = min(max(xi, 0), W - 1);
        int yc = min(max(yi, 0), H - 1);
        float vv = valid ? img[(size_t)yc * W + xc] : 0.0f;
        sc += vv * (wxs[xx] * wys[yy]);
      }
  }
  out[((size_t)b * TOPK + r) * 2 + 0] = kx;
  out[((size_t)b * TOPK + r) * 2 + 1] = ky;
  out[(size_t)B * TOPK * 2 + (size_t)b * TOPK + r] = sc;
  out[(size_t)B * TOPK * 3 + (size_t)b * TOPK + r] = dsp;
}

}  // namespace

extern "C" void kernel_launch(void* const* d_in, const int* in_sizes, int n_in,
                              void* d_out, int out_size, void* d_ws, size_t ws_size,
                              hipStream_t stream) {
  const float* scores = (const float*)d_in[0];
  float* out = (float*)d_out;
  char* ws = (char*)d_ws;

  uint32_t* cnt = (uint32_t*)(ws + OFF_CNT);
  uint32_t* cand_count = cnt;                    // [B]
  uint32_t* sel_count  = cnt + 8;                // [B]
  uint64_t* thr_key    = (uint64_t*)(cnt + 16);  // [B]
  uint32_t* ghist = (uint32_t*)(ws + OFF_GHIST);
  uint32_t* rankg = (uint32_t*)(ws + OFF_RANK);
  uint64_t* sel  = (uint64_t*)(ws + OFF_SEL);
  uint64_t* cand = (uint64_t*)(ws + OFF_CAND);

  k_zero<<<256, 256, 0, stream>>>((float4*)ws, (int)(ZERO_BYTES / 16));
  k_nms<<<dim3(W / 64, H / 64, B), 256, 0, stream>>>(scores, cand, cand_count, ghist);
  k_findthr<<<B, 1024, 0, stream>>>(ghist, thr_key);
  k_compact<<<dim3(CAND_CAP / 1024, B), 1024, 0, stream>>>(cand, cand_count, thr_key, sel, sel_count);
  k_rank_part<<<dim3(SEL_CAP / RK_ME, SEL_CAP / RK_CH, B), RK_ME, 0, stream>>>(sel, sel_count, rankg);
  k_refine<<<dim3(SEL_CAP * 8 / 256, B), 256, 0, stream>>>(scores, sel, sel_count, rankg, out);
}

// Round 12
// 225.692 us; speedup vs baseline: 1.4854x; 1.4854x over previous
//
#include <hip/hip_runtime.h>
#include <stdint.h>

namespace {

constexpr int B = 8;
constexpr int H = 1024;
constexpr int W = 1024;
constexpr int TOPK = 4096;
constexpr int CAND_CAP = 131072;  // per batch
constexpr int SEL_CAP = 8192;     // per batch (expected n ~ 6k)
constexpr int LIST_CAP = 320;     // per 64x64 tile (avg ~164 survivors; fallback below)
constexpr int HIST_N = 32768;     // 17-bit key prefix = score_bits>>15
constexpr int NHB = 48;           // hist slice blocks per batch

// fused-NMS tile (R7-bench winner, 69 µs): 64x64 interior, radius-12 staged halo,
// rows padded to 92. Masks bitpacked 1 bit/px in u32 words, suppression applied
// on-the-fly inside score passes; S stays original (emit reads it directly).
constexpr int RROWS = 92;   // staged score rows
constexpr int NG = 22;      // float4 col-groups (88 cols)
constexpr int STR = 88;     // score row stride (floats)
constexpr int MW4 = 4;      // bitpacked mask words per row (96 bits; word 3 = pad)
constexpr int NSTRIP = 11;  // 11 strips x 8 output rows = rows 2..89
constexpr int NUNIT = NG * NSTRIP;  // 242 <= 256

// rank kernel tiling (R9-bench winner: me x chunk tiled grid, 2048 blocks)
constexpr int RK_ME = 256;
constexpr int RK_CH = 1024;

// workspace layout (bytes)
constexpr size_t OFF_CNT   = 0;                                    // 4 KiB
constexpr size_t OFF_GHIST = 4096;                                 // B*HIST_N*4 = 1 MiB
constexpr size_t OFF_RANK  = OFF_GHIST + (size_t)B * HIST_N * 4;   // B*SEL_CAP*4 = 256 KiB
constexpr size_t OFF_SEL   = OFF_RANK + (size_t)B * SEL_CAP * 4;   // B*SEL_CAP*8 = 512 KiB
constexpr size_t OFF_CAND  = OFF_SEL + (size_t)B * SEL_CAP * 8;    // 8 MiB
constexpr size_t ZERO_BYTES = OFF_SEL;  // cnt page + ghist + rank

__device__ __forceinline__ float max5(float a, float b, float c, float d, float e) {
  return fmaxf(fmaxf(fmaxf(a, b), fmaxf(c, d)), e);
}
__device__ __forceinline__ float4 ld4(const float* p) {
  return *reinterpret_cast<const float4*>(p);
}

// One unit: col-group G in [0,22), strip s in [0,11) -> staged rows r0..r0+7.
// PASS 0: mask0 = (sc == max5x5(sc)) & valid          -> atomicOr MA
// PASS 1: mask1 = mask0 | (newmax(sup?0:sc) & ~sup1)  -> atomicOr MA (in place)
// PASS 2: final = mask1 | (newmax(sup?0:sc) & ~sup2)  -> emit keys
template <int PASS>
__device__ __forceinline__ void score_pass(
    int u, int x0, int y0, const float* __restrict__ S,
    const uint32_t* __restrict__ SUP, uint32_t* __restrict__ MA,
    uint64_t* list, uint32_t* cnt_loc, uint64_t* cand, uint32_t* cand_count, int b) {
  const int G = u % NG, s = u / NG;
  const int r0 = 2 + 8 * s;
  const int gx0 = x0 - 12 + 4 * G;
  uint32_t colm = 0;
#pragma unroll
  for (int j = 0; j < 4; ++j)
    if ((unsigned)(gx0 + j) < (unsigned)W) colm |= 1u << j;
  // suppression window: bits 0..3 -> cols of a, 4..7 -> d, 8..11 -> e
  const int p = 4 * G - 4;
  const int pw = (p < 0) ? 0 : (p >> 5);
  const int psh = (p < 0) ? 0 : (p & 31);
  const int pls = (p < 0) ? -p : 0;

  float4 hw[5], cw[5];
  uint32_t sn[5];
#pragma unroll
  for (int k = 0; k < 12; ++k) {
    const int rr = r0 - 2 + k;
    const float* rowp = S + rr * STR + 4 * G;
    float4 d = ld4(rowp);
    float4 a = (G > 0) ? ld4(rowp - 4) : d;  // garbage-only cols, safe
    float4 e = (G < NG - 1) ? ld4(rowp + 4) : d;
    uint32_t supn = 0;
    if (PASS != 0) {
      const uint32_t* srow = SUP + rr * MW4;
      uint64_t X = (uint64_t)srow[pw] | ((uint64_t)srow[pw + 1] << 32);
      uint64_t win = pls ? (X << pls) : (X >> psh);
      if (win & 0x001u) a.x = 0.f;
      if (win & 0x002u) a.y = 0.f;
      if (win & 0x004u) a.z = 0.f;
      if (win & 0x008u) a.w = 0.f;
      if (win & 0x010u) d.x = 0.f;
      if (win & 0x020u) d.y = 0.f;
      if (win & 0x040u) d.z = 0.f;
      if (win & 0x080u) d.w = 0.f;
      if (win & 0x100u) e.x = 0.f;
      if (win & 0x200u) e.y = 0.f;
      if (win & 0x400u) e.z = 0.f;
      if (win & 0x800u) e.w = 0.f;
      supn = (uint32_t)(win >> 4) & 0xFu;
    }
    float4 hm;
    hm.x = max5(a.z, a.w, d.x, d.y, d.z);
    hm.y = max5(a.w, d.x, d.y, d.z, d.w);
    hm.z = max5(d.x, d.y, d.z, d.w, e.x);
    hm.w = max5(d.y, d.z, d.w, e.x, e.y);
    hw[k % 5] = hm;
    cw[k % 5] = d;
    sn[k % 5] = supn;
    if (k >= 4) {
      const int rq = r0 + k - 4;
      const int gy = y0 - 12 + rq;
      float4 vm;
      vm.x = max5(hw[0].x, hw[1].x, hw[2].x, hw[3].x, hw[4].x);
      vm.y = max5(hw[0].y, hw[1].y, hw[2].y, hw[3].y, hw[4].y);
      vm.z = max5(hw[0].z, hw[1].z, hw[2].z, hw[3].z, hw[4].z);
      vm.w = max5(hw[0].w, hw[1].w, hw[2].w, hw[3].w, hw[4].w);
      float4 c = cw[(k + 3) % 5];  // center row rq (masked value for PASS 1/2)
      uint32_t nm = (uint32_t)(c.x == vm.x) | ((uint32_t)(c.y == vm.y) << 1) |
                    ((uint32_t)(c.z == vm.z) << 2) | ((uint32_t)(c.w == vm.w) << 3);
      nm &= ((unsigned)gy < (unsigned)H) ? colm : 0u;
      const int widx = rq * MW4 + (G >> 3);
      const int shift = 4 * (G & 7);
      if (PASS == 0) {
        if (nm) atomicOr(&MA[widx], nm << shift);
      } else if (PASS == 1) {
        uint32_t v = nm & ~sn[(k + 3) % 5];
        if (v) atomicOr(&MA[widx], v << shift);
      } else {
        uint32_t fin = ((MA[widx] >> shift) & 0xFu) | (nm & ~sn[(k + 3) % 5]);
        if (fin && G >= 3 && G < 19 && rq >= 12 && rq < 76 && gy >= 2 && gy < H - 2) {
#pragma unroll
          for (int j = 0; j < 4; ++j) {
            if ((fin >> j) & 1u) {
              int gx = gx0 + j;
              if (gx >= 2 && gx < W - 2) {
                float sval = S[rq * STR + 4 * G + j];  // original (unmasked) score
                if (sval > 0.0f) {
                  uint32_t bits = __float_as_uint(sval);
                  uint32_t flat = (uint32_t)(gy * W + gx);
                  uint64_t key = ((uint64_t)bits << 32) | (uint64_t)(0xFFFFFFFFu - flat);
                  uint32_t pos = atomicAdd(cnt_loc, 1u);
                  if (pos < (uint32_t)LIST_CAP) {
                    list[pos] = key;
                  } else {  // tie overflow: direct global append (rare)
                    uint32_t pp = atomicAdd(&cand_count[b], 1u);
                    if (pp < (uint32_t)CAND_CAP) cand[(size_t)b * CAND_CAP + pp] = key;
                  }
                }
              }
            }
          }
        }
      }
    }
  }
}

// bit-dilate r=2: SOUT |= any(MIN in 5x5) & valid (nibble per (row, G))
__device__ __forceinline__ void dilate_pass(int u, int x0, int y0,
                                            const uint32_t* __restrict__ MIN_,
                                            uint32_t* __restrict__ SOUT) {
  const int G = u % NG, s = u / NG;
  const int r0 = 2 + 8 * s;
  const int gx0 = x0 - 12 + 4 * G;
  uint32_t colm = 0;
#pragma unroll
  for (int j = 0; j < 4; ++j)
    if ((unsigned)(gx0 + j) < (unsigned)W) colm |= 1u << j;
  const int p = 4 * G - 2;  // window bit m = staged col p+m
  const int pw = (p < 0) ? 0 : (p >> 5);
  const int psh = (p < 0) ? 0 : (p & 31);
  const int pls = (p < 0) ? -p : 0;
  uint32_t ring[5];
#pragma unroll
  for (int k = 0; k < 12; ++k) {
    const int rr = r0 - 2 + k;
    const uint32_t* srow = MIN_ + rr * MW4;
    uint64_t X = (uint64_t)srow[pw] | ((uint64_t)srow[pw + 1] << 32);
    uint64_t win = pls ? (X << pls) : (X >> psh);
    uint64_t t = win | (win >> 1) | (win >> 2) | (win >> 3) | (win >> 4);
    ring[k % 5] = (uint32_t)t & 0xFu;
    if (k >= 4) {
      const int rq = r0 + k - 4;
      const int gy = y0 - 12 + rq;
      uint32_t nib = ring[0] | ring[1] | ring[2] | ring[3] | ring[4];
      nib &= ((unsigned)gy < (unsigned)H) ? colm : 0u;
      if (nib) atomicOr(&SOUT[rq * MW4 + (G >> 3)], nib << (4 * (G & 7)));
    }
  }
}

// ---------------- fused 5-pass NMS + candidate emit ----------------------------------
__global__ void __launch_bounds__(256, 4) k_nms(const float* __restrict__ scores,
                                                uint64_t* __restrict__ cand,
                                                uint32_t* __restrict__ cand_count) {
  __shared__ float S[RROWS * STR];        // 32.4 KB
  __shared__ uint32_t MAs[RROWS * MW4];   // 1.47 KB (mask0, then mask1 in place)
  __shared__ uint32_t SP1[RROWS * MW4];   // 1.47 KB
  __shared__ uint32_t SP2[RROWS * MW4];   // 1.47 KB
  __shared__ uint64_t list[LIST_CAP];     // 2.5 KB   -> total 39.4 KB, 4 blk/CU
  __shared__ uint32_t cnt_loc, base_g;
  const int b = blockIdx.z;
  const int x0 = blockIdx.x * 64, y0 = blockIdx.y * 64;
  const int tid = threadIdx.x;
  const float* img = scores + (size_t)b * H * W;
  if (tid == 0) cnt_loc = 0;

  for (int u = tid; u < RROWS * NG; u += 256) {
    int r = u / NG, G = u % NG;
    int gy = y0 - 12 + r, gx = x0 - 12 + 4 * G;
    float4 v;
    if ((unsigned)gy < (unsigned)H && (unsigned)gx < (unsigned)W)
      v = ld4(img + (size_t)gy * W + gx);
    else
      v = make_float4(-INFINITY, -INFINITY, -INFINITY, -INFINITY);
    *reinterpret_cast<float4*>(&S[r * STR + 4 * G]) = v;
  }
  for (int i = tid; i < RROWS * MW4; i += 256) {
    MAs[i] = 0;
    SP1[i] = 0;
    SP2[i] = 0;
  }
  __syncthreads();
  if (tid < NUNIT)
    score_pass<0>(tid, x0, y0, S, nullptr, MAs, nullptr, nullptr, nullptr, nullptr, b);
  __syncthreads();
  if (tid < NUNIT) dilate_pass(tid, x0, y0, MAs, SP1);
  __syncthreads();
  if (tid < NUNIT)
    score_pass<1>(tid, x0, y0, S, SP1, MAs, nullptr, nullptr, nullptr, nullptr, b);
  __syncthreads();
  if (tid < NUNIT) dilate_pass(tid, x0, y0, MAs, SP2);
  __syncthreads();
  if (tid < NUNIT)
    score_pass<2>(tid, x0, y0, S, SP2, MAs, list, &cnt_loc, cand, cand_count, b);
  __syncthreads();
  uint32_t nblk = cnt_loc;
  uint32_t nmain = nblk < (uint32_t)LIST_CAP ? nblk : (uint32_t)LIST_CAP;
  if (tid == 0) base_g = atomicAdd(&cand_count[b], nmain);
  __syncthreads();
  uint32_t bg = base_g;
  for (uint32_t i = tid; i < nmain; i += 256) {
    uint32_t pp = bg + i;
    if (pp < (uint32_t)CAND_CAP) cand[(size_t)b * CAND_CAP + pp] = list[i];
  }
}

// ---------------- zero scratch -------------------------------------------------------
__global__ void __launch_bounds__(256) k_zero(float4* __restrict__ p, int n4) {
  int i = blockIdx.x * 256 + threadIdx.x;
  const int stride = gridDim.x * 256;
  const float4 z = make_float4(0.f, 0.f, 0.f, 0.f);
  for (; i < n4; i += stride) p[i] = z;
}

// ---------------- grid-parallel 17-bit histogram with wave match-any -----------------
// The ballot-aggregation is load-bearing: score distribution is heavily skewed
// (max-of-25 uniforms), so unaggregated atomics serialize on the hot buckets
// (R11 post-mortem: fused per-candidate atomics cost k_nms 69 -> 217 µs).
__global__ void __launch_bounds__(256) k_hist(const uint64_t* __restrict__ cand,
                                              const uint32_t* __restrict__ cand_count,
                                              uint32_t* __restrict__ ghist) {
  const int b = blockIdx.y;
  uint32_t n = cand_count[b];
  if (n > (uint32_t)CAND_CAP) n = CAND_CAP;
  uint32_t* gh = ghist + (size_t)b * HIST_N;
  const uint64_t* cb = cand + (size_t)b * CAND_CAP;
  const int lane = threadIdx.x & 63;
  for (uint32_t i = blockIdx.x * 256 + threadIdx.x;; i += NHB * 256) {
    bool valid = i < n;
    uint64_t act = __ballot(valid);
    if (!act) break;
    uint32_t bkt = 0;
    if (valid) bkt = (uint32_t)(cb[i] >> 47);  // = score_bits >> 15, < 32768
    uint64_t peers = act;
#pragma unroll
    for (int bit = 0; bit < 15; ++bit) {
      uint64_t bb = __ballot((bkt >> bit) & 1u);
      peers &= ((bkt >> bit) & 1u) ? bb : ~bb;
    }
    if (valid && (__ffsll((unsigned long long)peers) - 1) == lane)
      atomicAdd(&gh[bkt], (uint32_t)__popcll((unsigned long long)peers));
  }
}

// ---------------- find threshold bucket ----------------------------------------------
__global__ void __launch_bounds__(1024) k_findthr(const uint32_t* __restrict__ ghist,
                                                  uint64_t* __restrict__ thr_key) {
  __shared__ uint32_t part[1024];
  __shared__ int shT;
  __shared__ uint32_t sh_above;
  const int b = blockIdx.x, t = threadIdx.x;
  const uint32_t* gh = ghist + (size_t)b * HIST_N;
  uint32_t s = 0;
#pragma unroll 4
  for (int i = 0; i < 32; ++i) s += gh[t * 32 + i];
  part[t] = s;
  if (t == 0) { shT = -1; sh_above = 0; }
  __syncthreads();
  for (int d = 1; d < 1024; d <<= 1) {  // suffix sum: part[t] = sum_{t'>=t}
    uint32_t v = (t + d < 1024) ? part[t + d] : 0u;
    __syncthreads();
    part[t] += v;
    __syncthreads();
  }
  if (part[0] < (uint32_t)TOPK) {
    if (t == 0) thr_key[b] = 0ull;  // fewer than TOPK candidates: select all
    return;
  }
  {
    uint32_t mine = part[t];
    uint32_t nxt = (t + 1 < 1024) ? part[t + 1] : 0u;
    if (mine >= (uint32_t)TOPK && nxt < (uint32_t)TOPK) { shT = t; sh_above = nxt; }
  }
  __syncthreads();
  if (t == 0) {
    const int T = shT;
    uint32_t run = sh_above;
    int bkt = T * 32;
    for (int i = 31; i >= 0; --i) {
      run += gh[T * 32 + i];
      if (run >= (uint32_t)TOPK) { bkt = T * 32 + i; break; }
    }
    thr_key[b] = (uint64_t)bkt << 47;
  }
}

// ---------------- compact ------------------------------------------------------------
__global__ void __launch_bounds__(1024) k_compact(const uint64_t* __restrict__ cand,
                                                  const uint32_t* __restrict__ cand_count,
                                                  const uint64_t* __restrict__ thr_key,
                                                  uint64_t* __restrict__ sel,
                                                  uint32_t* __restrict__ sel_count) {
  __shared__ uint64_t list[1024];
  __shared__ uint32_t cnt_loc;
  __shared__ uint32_t base_g;
  const int b = blockIdx.y;
  uint32_t n = cand_count[b];
  if (n > (uint32_t)CAND_CAP) n = CAND_CAP;
  const int tid = threadIdx.x;
  if (tid == 0) cnt_loc = 0;
  __syncthreads();
  uint32_t i = blockIdx.x * 1024 + tid;
  if (i < n) {
    uint64_t key = cand[(size_t)b * CAND_CAP + i];
    if (key >= thr_key[b]) {
      uint32_t pos = atomicAdd(&cnt_loc, 1u);
      list[pos] = key;
    }
  }
  __syncthreads();
  uint32_t nblk = cnt_loc;
  if (tid == 0 && nblk > 0) base_g = atomicAdd(&sel_count[b], nblk);
  __syncthreads();
  if (nblk > 0 && (uint32_t)tid < nblk) {
    uint32_t pp = base_g + tid;
    if (pp < (uint32_t)SEL_CAP) sel[(size_t)b * SEL_CAP + pp] = list[tid];
  }
}

// ---------------- tiled partial ranking (R9-bench winner) ----------------------------
// rank[me] = #{keys > me}; keys distinct => permutation => exact JAX top_k order.
__global__ void __launch_bounds__(RK_ME) k_rank_part(const uint64_t* __restrict__ sel,
                                                     const uint32_t* __restrict__ sel_count,
                                                     uint32_t* __restrict__ rankg) {
  __shared__ uint64_t keys[RK_CH];  // 8 KiB
  const int b = blockIdx.z;
  uint32_t n = sel_count[b];
  if (n > (uint32_t)SEL_CAP) n = SEL_CAP;
  const uint32_t me0 = blockIdx.x * RK_ME;
  const uint32_t c0 = blockIdx.y * RK_CH;
  if (me0 >= n || c0 >= n) return;
  const uint64_t* sb = sel + (size_t)b * SEL_CAP;
  uint32_t clen = n - c0;
  if (clen > (uint32_t)RK_CH) clen = RK_CH;
  for (uint32_t i = threadIdx.x; i < clen; i += RK_ME) keys[i] = sb[c0 + i];
  __syncthreads();
  const uint32_t me = me0 + threadIdx.x;
  if (me >= n) return;
  const uint64_t kme = sb[me];
  uint32_t rank = 0;
  uint32_t i = 0;
  for (; i + 8 <= clen; i += 8) {
    rank += (keys[i] > kme);
    rank += (keys[i + 1] > kme);
    rank += (keys[i + 2] > kme);
    rank += (keys[i + 3] > kme);
    rank += (keys[i + 4] > kme);
    rank += (keys[i + 5] > kme);
    rank += (keys[i + 6] > kme);
    rank += (keys[i + 7] > kme);
  }
  for (; i < clen; ++i) rank += (keys[i] > kme);
  if (rank) atomicAdd(&rankg[(size_t)b * SEL_CAP + me], rank);
}

// ---------------- refinement fused with scatter: 8 lanes per selected key ------------
__global__ void __launch_bounds__(256) k_refine(const float* __restrict__ scores,
                                                const uint64_t* __restrict__ sel,
                                                const uint32_t* __restrict__ sel_count,
                                                const uint32_t* __restrict__ rankg,
                                                float* __restrict__ out) {
  const int b = blockIdx.y;
  uint32_t n = sel_count[b];
  if (n > (uint32_t)SEL_CAP) n = SEL_CAP;
  int gid = blockIdx.x * 256 + threadIdx.x;
  int si = gid >> 3, ln = gid & 7;
  if ((uint32_t)si >= n) return;
  uint32_t r = rankg[(size_t)b * SEL_CAP + si];
  if (r >= (uint32_t)TOPK) return;
  uint64_t key = sel[(size_t)b * SEL_CAP + si];
  uint32_t flat = 0xFFFFFFFFu - (uint32_t)(key & 0xFFFFFFFFull);
  if (flat >= (uint32_t)(H * W)) flat = 0;
  const int ix = (int)(flat % W);
  const int iy = (int)(flat / W);
  const float* img = scores + (size_t)b * H * W;

  const int nt = (ln == 0) ? 4 : 3;
  float v[4];
  float mymax = -INFINITY;
#pragma unroll
  for (int i = 0; i < 4; ++i) {
    if (i < nt) {
      int t = ln + 8 * i;
      int y = iy + t / 5 - 2, x = ix + t % 5 - 2;
      float val = ((unsigned)x < (unsigned)W && (unsigned)y < (unsigned)H)
                      ? img[(size_t)y * W + x] : 0.0f;
      v[i] = val;
      mymax = fmaxf(mymax, val);
    }
  }
#pragma unroll
  for (int m = 1; m < 8; m <<= 1) mymax = fmaxf(mymax, __shfl_xor(mymax, m));
  float e[4];
  float sum = 0.f, sx = 0.f, sy = 0.f;
#pragma unroll
  for (int i = 0; i < 4; ++i) {
    if (i < nt) {
      int t = ln + 8 * i;
      float ev = expf((v[i] - mymax) / 0.1f);
      e[i] = ev;
      sum += ev;
      sx += ev * (float)(t % 5 - 2);
      sy += ev * (float)(t / 5 - 2);
    }
  }
#pragma unroll
  for (int m = 1; m < 8; m <<= 1) {
    sum += __shfl_xor(sum, m);
    sx += __shfl_xor(sx, m);
    sy += __shfl_xor(sy, m);
  }
  float rx = sx / sum, ry = sy / sum;
  float dsp = 0.f;
#pragma unroll
  for (int i = 0; i < 4; ++i) {
    if (i < nt) {
      int t = ln + 8 * i;
      float dx = ((float)(t % 5 - 2) - rx) * 0.5f;
      float dy = ((float)(t / 5 - 2) - ry) * 0.5f;
      dsp += e[i] * (dx * dx + dy * dy);
    }
  }
#pragma unroll
  for (int m = 1; m < 8; m <<= 1) dsp += __shfl_xor(dsp, m);
  if (ln != 0) return;
  dsp /= sum;
  float kx = ((float)ix + rx) / 1023.0f * 2.0f - 1.0f;
  float ky = ((float)iy + ry) / 1023.0f * 2.0f - 1.0f;
  float px = (kx + 1.0f) * 0.5f * 1023.0f;
  float py = (ky + 1.0f) * 0.5f * 1023.0f;
  float x0f = floorf(px), y0f = floorf(py);
  float wx1 = px - x0f, wx0 = 1.0f - wx1;
  float wy1 = py - y0f, wy0 = 1.0f - wy1;
  int x0 = (int)x0f, y0 = (int)y0f;
  float sc = 0.0f;
  {
    int xs[2] = {x0, x0 + 1};
    int ys[2] = {y0, y0 + 1};
    float wxs[2] = {wx0, wx1};
    float wys[2] = {wy0, wy1};
#pragma unroll
    for (int yy = 0; yy < 2; ++yy)
#pragma unroll
      for (int xx = 0; xx < 2; ++xx) {
        int xi = xs[xx], yi = ys[yy];
        bool valid = (xi >= 0 && xi < W && yi >= 0 && yi < H);
        int xc = min(max(xi, 0), W - 1);
        int yc = min(max(yi, 0), H - 1);
        float vv = valid ? img[(size_t)yc * W + xc] : 0.0f;
        sc += vv * (wxs[xx] * wys[yy]);
      }
  }
  out[((size_t)b * TOPK + r) * 2 + 0] = kx;
  out[((size_t)b * TOPK + r) * 2 + 1] = ky;
  out[(size_t)B * TOPK * 2 + (size_t)b * TOPK + r] = sc;
  out[(size_t)B * TOPK * 3 + (size_t)b * TOPK + r] = dsp;
}

}  // namespace

extern "C" void kernel_launch(void* const* d_in, const int* in_sizes, int n_in,
                              void* d_out, int out_size, void* d_ws, size_t ws_size,
                              hipStream_t stream) {
  const float* scores = (const float*)d_in[0];
  float* out = (float*)d_out;
  char* ws = (char*)d_ws;

  uint32_t* cnt = (uint32_t*)(ws + OFF_CNT);
  uint32_t* cand_count = cnt;                    // [B]
  uint32_t* sel_count  = cnt + 8;                // [B]
  uint64_t* thr_key    = (uint64_t*)(cnt + 16);  // [B]
  uint32_t* ghist = (uint32_t*)(ws + OFF_GHIST);
  uint32_t* rankg = (uint32_t*)(ws + OFF_RANK);
  uint64_t* sel  = (uint64_t*)(ws + OFF_SEL);
  uint64_t* cand = (uint64_t*)(ws + OFF_CAND);

  k_zero<<<256, 256, 0, stream>>>((float4*)ws, (int)(ZERO_BYTES / 16));
  k_nms<<<dim3(W / 64, H / 64, B), 256, 0, stream>>>(scores, cand, cand_count);
  k_hist<<<dim3(NHB, B), 256, 0, stream>>>(cand, cand_count, ghist);
  k_findthr<<<B, 1024, 0, stream>>>(ghist, thr_key);
  k_compact<<<dim3(CAND_CAP / 1024, B), 1024, 0, stream>>>(cand, cand_count, thr_key, sel, sel_count);
  k_rank_part<<<dim3(SEL_CAP / RK_ME, SEL_CAP / RK_CH, B), RK_ME, 0, stream>>>(sel, sel_count, rankg);
  k_refine<<<dim3(SEL_CAP * 8 / 256, B), 256, 0, stream>>>(scores, sel, sel_count, rankg, out);
}